// Round 5
// baseline (551.302 us; speedup 1.0000x reference)
//
#include <hip/hip_runtime.h>

#ifndef __has_builtin
#define __has_builtin(x) 0
#endif

#define NOBS_OS 8
#define NOBS_TS 6
#define HID 128
#define NACT 9
#define BTOT 32768
#define NTS 32
#define ROWS 32        // batch rows per tile
#define NTILES 1024    // 1024*32 = 32768
#define MAIN_BLOCKS 512
#define BLOCK 256      // 4 waves; wave w owns hidden cols [32w,32w+32)

// workspace layout (int32 offsets)
#define HIST_OFF 0
#define OFFS_OFF 64
#define LEN_OFF 128
#define PERM_OFF (128 + BTOT)

typedef __attribute__((ext_vector_type(8))) short short8;
typedef __attribute__((ext_vector_type(4))) float f32x4;
typedef __attribute__((ext_vector_type(16))) float f32x16;

__device__ inline unsigned short f2bf(float x) {
  unsigned int u = __float_as_uint(x);
  u += 0x7FFFu + ((u >> 16) & 1u);
  return (unsigned short)(u >> 16);
}

__device__ inline float fexp2(float x) {
#if __has_builtin(__builtin_amdgcn_exp2f)
  return __builtin_amdgcn_exp2f(x);
#else
  return exp2f(x);
#endif
}
__device__ inline float frcp_(float x) {
#if __has_builtin(__builtin_amdgcn_rcpf)
  return __builtin_amdgcn_rcpf(x);
#else
  return 1.0f / x;
#endif
}
__device__ inline float fsigmoid(float x) {
  return frcp_(1.0f + fexp2(x * -1.44269504088896340736f));
}
__device__ inline float ftanh_(float x) {
  float e = fexp2(x * -2.88539008177792681472f); // exp(-2x)
  return (1.0f - e) * frcp_(1.0f + e);
}

__device__ inline short8 pack8(f32x4 a, f32x4 b) {
  short8 r;
  r[0] = (short)f2bf(a[0]); r[1] = (short)f2bf(a[1]);
  r[2] = (short)f2bf(a[2]); r[3] = (short)f2bf(a[3]);
  r[4] = (short)f2bf(b[0]); r[5] = (short)f2bf(b[1]);
  r[6] = (short)f2bf(b[2]); r[7] = (short)f2bf(b[3]);
  return r;
}

// ---- counting-sort pre-pass (LDS-aggregated) ----------------------------
__global__ void zero_hist_kernel(int* ws) {
  if (threadIdx.x < 128) ws[threadIdx.x] = 0;
}

__global__ void count_kernel(const float* __restrict__ s, int* __restrict__ ws) {
  __shared__ int lh[NTS + 1];
  const int tid = threadIdx.x;
  if (tid <= NTS) lh[tid] = 0;
  __syncthreads();
  const int row = blockIdx.x * 256 + tid;
  const float* p = s + (size_t)row * 200 + NOBS_OS;
  int lo = 0, hi = NTS;
  while (lo < hi) {
    const int mid = (lo + hi) >> 1;
    const float v = p[mid * NOBS_TS];
    if (v == v) lo = mid + 1; else hi = mid;
  }
  ws[LEN_OFF + row] = lo;
  atomicAdd(&lh[lo], 1);
  __syncthreads();
  if (tid <= NTS && lh[tid]) atomicAdd(&ws[HIST_OFF + tid], lh[tid]);
}

__global__ void scan_kernel(int* ws) {
  if (threadIdx.x == 0) {
    int acc = 0;
    for (int i = 0; i <= NTS; ++i) {
      ws[OFFS_OFF + i] = acc;
      acc += ws[HIST_OFF + i];
    }
  }
}

__global__ void scatter_kernel(int* __restrict__ ws) {
  __shared__ int lh[NTS + 1];
  __shared__ int lbase[NTS + 1];
  const int tid = threadIdx.x;
  if (tid <= NTS) lh[tid] = 0;
  __syncthreads();
  const int row = blockIdx.x * 256 + tid;
  const int len = ws[LEN_OFF + row];
  const int lrank = atomicAdd(&lh[len], 1);
  __syncthreads();
  if (tid <= NTS && lh[tid]) lbase[tid] = atomicAdd(&ws[OFFS_OFF + tid], lh[tid]);
  __syncthreads();
  ws[PERM_OFF + lbase[len] + lrank] = row;
}

// ---- main fused kernel --------------------------------------------------
// A-frag buffers (32 rows x K) with XOR bank swizzle:
//   logical group for elem (m,k): G = (k>>4)*64 + ((k>>3)&1)*32 + m
//   stored at G' = G ^ ((G>>5)&3); u16 idx = G'*8 + (k&7)
// Reader (lane L, k-tile kt): idx = kt*512 + (L ^ (half + 2*(kt&1)))*8, 8 elems (b128).
// Writer (C-layout, col k=n_glob, row m=(r&3)+8*(r>>2)+4*half):
//   idx = wbase[r&3] + (r>>2)*64, wbase[v] = C0*8 + half*32 + (k&7) + ((v^X)*8),
//   C0 = (k>>4)*64 + ((k>>3)&1)*32, X = (C0>>5)&3.  (hand-verified both ways)

#define ACT_BODY(DO_CAP)                                                     \
  _Pragma("unroll")                                                          \
  for (int r = 0; r < 16; ++r) {                                             \
    const float iv = fsigmoid(acc[0][r]);                                    \
    const float fv = fsigmoid(acc[1][r]);                                    \
    const float gv = ftanh_(acc[2][r]);                                      \
    const float ov = fsigmoid(acc[3][r]);                                    \
    const float cv = fv * cc[r] + iv * gv;                                   \
    cc[r] = cv;                                                              \
    const unsigned short hb16 = f2bf(ov * ftanh_(cv));                       \
    hw[wbase[r & 3] + ((r >> 2) << 6)] = hb16;                               \
    if (DO_CAP) {                                                            \
      if ((int)((tpck[r >> 2] >> ((r & 3) * 8)) & 255u) == t)                \
        xtsb[wbase[r & 3] + ((r >> 2) << 6)] = hb16;                         \
    }                                                                        \
  }

__global__ __launch_bounds__(BLOCK, 2) void recdqn_kernel(
    const float* __restrict__ s, const float* __restrict__ W_os,
    const float* __restrict__ b_os, const float* __restrict__ W_ih,
    const float* __restrict__ W_hh, const float* __restrict__ b_ih,
    const float* __restrict__ b_hh, const float* __restrict__ W_ts,
    const float* __restrict__ b_ts, const float* __restrict__ W_c1,
    const float* __restrict__ b_c1, const float* __restrict__ W_c2,
    const float* __restrict__ b_c2, const int* __restrict__ ws,
    float* __restrict__ out) {
  __shared__ unsigned short x_st[ROWS * 264]; // [row][t][8] bf16
  __shared__ unsigned short hA[2][4096];      // h A-frag (K=128), double buffered
  __shared__ unsigned short xtsb[4096];       // captured h at t=len-1, A-frag
  __shared__ unsigned short xcat[8192];       // concat(x_OS, x_TS) A-frag (K=256)
  __shared__ unsigned short x2b[4096];        // W_c1 output A-frag (K=128)
  __shared__ int n_lds[ROWS];
  __shared__ int rid_s[ROWS];
  __shared__ int wlo_s, tmax_s;

  const int tid = threadIdx.x;
  const int L = tid & 63;
  const int w = tid >> 6;     // wave 0..3: hidden cols [32w, 32w+32)
  const int half = L >> 5;
  const int nl = L & 31;
  const int ng = (w << 5) | nl; // this lane's hidden/output column

  const short8 z8 = {0, 0, 0, 0, 0, 0, 0, 0};

  // ---- one-time: W_hh/W_ih B-fragments + combined bias, register-resident.
  // B-frag layout (mirror of A): n = lane&31, k = kt*16 + half*8 + jj
  short8 Bh[4][9];
  float bias[4];
#pragma unroll
  for (int a = 0; a < 4; ++a) {
    const int n = (a << 7) + ng;
    bias[a] = b_ih[n] + b_hh[n];
#pragma unroll
    for (int kt = 0; kt < 8; ++kt) {
      const f32x4* p = (const f32x4*)(W_hh + n * HID + kt * 16 + half * 8);
      Bh[a][kt] = pack8(p[0], p[1]);
    }
    short8 fx = z8;
    if (half == 0) { // x-tile: k = jj, valid jj<6
      const float* px = W_ih + n * NOBS_TS;
      fx[0] = (short)f2bf(px[0]); fx[1] = (short)f2bf(px[1]);
      fx[2] = (short)f2bf(px[2]); fx[3] = (short)f2bf(px[3]);
      fx[4] = (short)f2bf(px[4]); fx[5] = (short)f2bf(px[5]);
    }
    Bh[a][8] = fx;
  }

  // write bases (k = ng)
  const int C0 = ((ng >> 4) << 6) + (((ng >> 3) & 1) << 5);
  const int X = (C0 >> 5) & 3;
  int wbase[4];
#pragma unroll
  for (int v = 0; v < 4; ++v)
    wbase[v] = (C0 << 3) + (half << 5) + (ng & 7) + ((v ^ X) << 3);

  // read addr xor variants (kt even / odd)
  const int ra0 = (L ^ half) << 3;
  const int ra1 = (L ^ (half + 2)) << 3;

  for (int tp = 0; tp < 2; ++tp) {
    // pair long and short tiles for load balance
    const int tt = (tp == 0) ? blockIdx.x : (NTILES - 1 - blockIdx.x);
    __syncthreads(); // protect LDS reuse across tiles

    if (tid < ROWS) {
      const int row = ws[PERM_OFF + tt * ROWS + tid];
      rid_s[tid] = row;
      n_lds[tid] = ws[LEN_OFF + row];
    }
    ((short8*)xtsb)[tid] = z8;
    ((short8*)xtsb)[tid + 256] = z8;
    __syncthreads();

    // ---- stage s_TS -> LDS bf16 (zeros past length)
#pragma unroll
    for (int it = 0; it < 4; ++it) {
      const int slot = tid + it * 256;
      const int r = slot >> 5, tq = slot & 31;
      short8 v = z8;
      if (tq < n_lds[r]) {
        const float2* ps = (const float2*)(s + (size_t)rid_s[r] * 200 + NOBS_OS + tq * NOBS_TS);
        const float2 A = ps[0], Bv = ps[1], Cv = ps[2];
        v[0] = (short)f2bf(A.x); v[1] = (short)f2bf(A.y);
        v[2] = (short)f2bf(Bv.x); v[3] = (short)f2bf(Bv.y);
        v[4] = (short)f2bf(Cv.x); v[5] = (short)f2bf(Cv.y);
      }
      *(short8*)&x_st[r * 264 + tq * 8] = v;
    }
    if (tid == 0) {
      int mx = 0, mp = 1000;
      for (int r = 0; r < ROWS; ++r) {
        const int len = n_lds[r];
        mx = max(mx, len);
        if (len > 0) mp = min(mp, len);
      }
      tmax_s = mx;
      wlo_s = mp - 1;
    }
    // per-lane packed tcap (u8, len=0 -> 255 never matches)
    unsigned tpck[4];
#pragma unroll
    for (int v = 0; v < 4; ++v) {
      unsigned pk = 0;
#pragma unroll
      for (int b = 0; b < 4; ++b) {
        const int m = b + (v << 3) + (half << 2);
        pk |= ((unsigned)((n_lds[m] - 1) & 255)) << (b * 8);
      }
      tpck[v] = pk;
    }
    __syncthreads();
    const int tmax = tmax_s, wlo = wlo_s;

    float cc[16];
#pragma unroll
    for (int i = 0; i < 16; ++i) cc[i] = 0.0f;

    // ---- LSTM time loop
    for (int t = 0; t < tmax; ++t) {
      f32x16 acc[4];
#pragma unroll
      for (int a = 0; a < 4; ++a) {
        const float bb = bias[a];
#pragma unroll
        for (int i = 0; i < 16; ++i) acc[a][i] = bb;
      }
      // x part (K-tile 8): lanes half==0 hold k=0..7 (6 valid)
      short8 ax = z8;
      if (half == 0) ax = *(const short8*)&x_st[nl * 264 + t * 8];
#pragma unroll
      for (int a = 0; a < 4; ++a)
        acc[a] = __builtin_amdgcn_mfma_f32_32x32x16_bf16(ax, Bh[a][8], acc[a], 0, 0, 0);
      if (t > 0) {
        const unsigned short* hb = hA[(t + 1) & 1];
#pragma unroll
        for (int kt = 0; kt < 8; ++kt) {
          const short8 ah = *(const short8*)&hb[(kt << 9) + ((kt & 1) ? ra1 : ra0)];
#pragma unroll
          for (int a = 0; a < 4; ++a)
            acc[a] = __builtin_amdgcn_mfma_f32_32x32x16_bf16(ah, Bh[a][kt], acc[a], 0, 0, 0);
        }
      }
      unsigned short* hw = hA[t & 1];
      const bool win = (t >= wlo);
      if (!win) {
        ACT_BODY(false)
      } else {
        ACT_BODY(true)
      }
      __syncthreads();
    }

    // ---- x_TS = relu(xts @ W_ts^T + b_ts) -> xcat k=128+ng
    {
      const float bb = b_ts[ng];
      f32x16 a2;
#pragma unroll
      for (int i = 0; i < 16; ++i) a2[i] = bb;
#pragma unroll
      for (int kt = 0; kt < 8; ++kt) {
        const short8 af = *(const short8*)&xtsb[(kt << 9) + ((kt & 1) ? ra1 : ra0)];
        const f32x4* p = (const f32x4*)(W_ts + ng * HID + kt * 16 + half * 8);
        a2 = __builtin_amdgcn_mfma_f32_32x32x16_bf16(af, pack8(p[0], p[1]), a2, 0, 0, 0);
      }
#pragma unroll
      for (int r = 0; r < 16; ++r)
        xcat[4096 + wbase[r & 3] + ((r >> 2) << 6)] = f2bf(fmaxf(a2[r], 0.0f));
    }

    // ---- x_OS = relu(s_OS @ W_os^T + b_os) -> xcat k=ng  (K=8, one tile)
    {
      short8 aos = z8, bos = z8;
      if (half == 0) {
        const f32x4* pa = (const f32x4*)(s + (size_t)rid_s[nl] * 200);
        aos = pack8(pa[0], pa[1]);
        const f32x4* pb = (const f32x4*)(W_os + ng * NOBS_OS);
        bos = pack8(pb[0], pb[1]);
      }
      const float bb = b_os[ng];
      f32x16 a2;
#pragma unroll
      for (int i = 0; i < 16; ++i) a2[i] = bb;
      a2 = __builtin_amdgcn_mfma_f32_32x32x16_bf16(aos, bos, a2, 0, 0, 0);
#pragma unroll
      for (int r = 0; r < 16; ++r)
        xcat[wbase[r & 3] + ((r >> 2) << 6)] = f2bf(fmaxf(a2[r], 0.0f));
    }
    __syncthreads();

    // ---- x = relu(xcat @ W_c1^T + b_c1) -> x2b (K=256)
    {
      const float bb = b_c1[ng];
      f32x16 a2;
#pragma unroll
      for (int i = 0; i < 16; ++i) a2[i] = bb;
#pragma unroll
      for (int kt = 0; kt < 16; ++kt) {
        const short8 af = *(const short8*)&xcat[(kt << 9) + ((kt & 1) ? ra1 : ra0)];
        const f32x4* p = (const f32x4*)(W_c1 + ng * 256 + kt * 16 + half * 8);
        a2 = __builtin_amdgcn_mfma_f32_32x32x16_bf16(af, pack8(p[0], p[1]), a2, 0, 0, 0);
      }
#pragma unroll
      for (int r = 0; r < 16; ++r)
        x2b[wbase[r & 3] + ((r >> 2) << 6)] = f2bf(fmaxf(a2[r], 0.0f));
    }
    __syncthreads();

    // ---- out = x2 @ W_c2^T + b_c2 (wave 0; cols nl<9 valid)
    if (w == 0) {
      const float bb = (nl < NACT) ? b_c2[nl] : 0.0f;
      f32x16 a2;
#pragma unroll
      for (int i = 0; i < 16; ++i) a2[i] = bb;
#pragma unroll
      for (int kt = 0; kt < 8; ++kt) {
        const short8 af = *(const short8*)&x2b[(kt << 9) + ((kt & 1) ? ra1 : ra0)];
        short8 bf = z8;
        if (nl < NACT) {
          const f32x4* p = (const f32x4*)(W_c2 + nl * HID + kt * 16 + half * 8);
          bf = pack8(p[0], p[1]);
        }
        a2 = __builtin_amdgcn_mfma_f32_32x32x16_bf16(af, bf, a2, 0, 0, 0);
      }
      if (nl < NACT) {
#pragma unroll
        for (int r = 0; r < 16; ++r) {
          const int m = (r & 3) + ((r >> 2) << 3) + (half << 2);
          out[(size_t)rid_s[m] * NACT + nl] = a2[r];
        }
      }
    }
  }
}

extern "C" void kernel_launch(void* const* d_in, const int* in_sizes, int n_in,
                              void* d_out, int out_size, void* d_ws, size_t ws_size,
                              hipStream_t stream) {
  (void)in_sizes; (void)n_in; (void)out_size; (void)ws_size;
  const float* s    = (const float*)d_in[0];
  const float* W_os = (const float*)d_in[1];
  const float* b_os = (const float*)d_in[2];
  const float* W_ih = (const float*)d_in[3];
  const float* W_hh = (const float*)d_in[4];
  const float* b_ih = (const float*)d_in[5];
  const float* b_hh = (const float*)d_in[6];
  const float* W_ts = (const float*)d_in[7];
  const float* b_ts = (const float*)d_in[8];
  const float* W_c1 = (const float*)d_in[9];
  const float* b_c1 = (const float*)d_in[10];
  const float* W_c2 = (const float*)d_in[11];
  const float* b_c2 = (const float*)d_in[12];
  int* ws = (int*)d_ws;
  float* outp = (float*)d_out;

  zero_hist_kernel<<<1, 128, 0, stream>>>(ws);
  count_kernel<<<BTOT / 256, 256, 0, stream>>>(s, ws);
  scan_kernel<<<1, 64, 0, stream>>>(ws);
  scatter_kernel<<<BTOT / 256, 256, 0, stream>>>(ws);
  recdqn_kernel<<<MAIN_BLOCKS, BLOCK, 0, stream>>>(
      s, W_os, b_os, W_ih, W_hh, b_ih, b_hh, W_ts, b_ts, W_c1, b_c1, W_c2,
      b_c2, ws, outp);
}

// Round 6
// 351.700 us; speedup vs baseline: 1.5675x; 1.5675x over previous
//
#include <hip/hip_runtime.h>

#ifndef __has_builtin
#define __has_builtin(x) 0
#endif

#define NOBS_OS 8
#define NOBS_TS 6
#define HID 128
#define NACT 9
#define BTOT 32768
#define NTS 32
#define ROWS 16        // batch rows per tile
#define NTILES 2048    // 2048*16 = 32768
#define PAIRS 1024     // one block per pair of adjacent sorted tiles
#define BLOCK 512      // 8 waves; wave w owns hidden cols [16w,16w+16)

// workspace layout (int32 offsets)
#define HIST_OFF 0
#define OFFS_OFF 64
#define LEN_OFF 128
#define PERM_OFF (128 + BTOT)

typedef __attribute__((ext_vector_type(8))) short short8;
typedef __attribute__((ext_vector_type(4))) float f32x4;

__device__ inline unsigned short f2bf(float x) {
  unsigned int u = __float_as_uint(x);
  u += 0x7FFFu + ((u >> 16) & 1u);
  return (unsigned short)(u >> 16);
}

__device__ inline float fexp2(float x) {
#if __has_builtin(__builtin_amdgcn_exp2f)
  return __builtin_amdgcn_exp2f(x);
#else
  return exp2f(x);
#endif
}
__device__ inline float frcp_(float x) {
#if __has_builtin(__builtin_amdgcn_rcpf)
  return __builtin_amdgcn_rcpf(x);
#else
  return 1.0f / x;
#endif
}

__device__ inline short8 pack8(f32x4 a, f32x4 b) {
  short8 r;
  r[0] = (short)f2bf(a[0]); r[1] = (short)f2bf(a[1]);
  r[2] = (short)f2bf(a[2]); r[3] = (short)f2bf(a[3]);
  r[4] = (short)f2bf(b[0]); r[5] = (short)f2bf(b[1]);
  r[6] = (short)f2bf(b[2]); r[7] = (short)f2bf(b[3]);
  return r;
}

__device__ inline short8 pack8s(const float* p, float s) {
  short8 r;
#pragma unroll
  for (int i = 0; i < 8; ++i) r[i] = (short)f2bf(p[i] * s);
  return r;
}

// ---- counting-sort pre-pass (LDS-aggregated, as R4) ---------------------
__global__ void zero_hist_kernel(int* ws) {
  if (threadIdx.x < 128) ws[threadIdx.x] = 0;
}

__global__ void count_kernel(const float* __restrict__ s, int* __restrict__ ws) {
  __shared__ int lh[NTS + 1];
  const int tid = threadIdx.x;
  if (tid <= NTS) lh[tid] = 0;
  __syncthreads();
  const int row = blockIdx.x * 256 + tid;
  const float* p = s + (size_t)row * 200 + NOBS_OS;
  int lo = 0, hi = NTS;
  while (lo < hi) {
    const int mid = (lo + hi) >> 1;
    const float v = p[mid * NOBS_TS];
    if (v == v) lo = mid + 1; else hi = mid;
  }
  ws[LEN_OFF + row] = lo;
  atomicAdd(&lh[lo], 1);
  __syncthreads();
  if (tid <= NTS && lh[tid]) atomicAdd(&ws[HIST_OFF + tid], lh[tid]);
}

__global__ void scan_kernel(int* ws) {
  if (threadIdx.x == 0) {
    int acc = 0;
    for (int i = 0; i <= NTS; ++i) {
      ws[OFFS_OFF + i] = acc;
      acc += ws[HIST_OFF + i];
    }
  }
}

__global__ void scatter_kernel(int* __restrict__ ws) {
  __shared__ int lh[NTS + 1];
  __shared__ int lbase[NTS + 1];
  const int tid = threadIdx.x;
  if (tid <= NTS) lh[tid] = 0;
  __syncthreads();
  const int row = blockIdx.x * 256 + tid;
  const int len = ws[LEN_OFF + row];
  const int lrank = atomicAdd(&lh[len], 1);
  __syncthreads();
  if (tid <= NTS && lh[tid]) lbase[tid] = atomicAdd(&ws[OFFS_OFF + tid], lh[tid]);
  __syncthreads();
  ws[PERM_OFF + lbase[len] + lrank] = row;
}

// ---- main fused kernel --------------------------------------------------
// A-frag layout in LDS (16 rows x K): elem idx = kt*512 + lane*8 + jj
// C-layout writes at column k: idx = (k>>5)*512 + ((k>>3)&3)*128 + m*8 + (k&7)
// Weights prescaled: i,f,o by -1/log2(e), g by -2/log2(e) so that
//   sigmoid(x) = rcp(1+exp2(y)),  tanh(x) = 2*rcp(1+exp2(y)) - 1.

#define GATES_X(CN, T)                                                       \
  f32x4 acc[4];                                                              \
  _Pragma("unroll") for (int a = 0; a < 4; ++a) {                            \
    const float bb = bias[a];                                                \
    f32x4 bv = {bb, bb, bb, bb};                                             \
    acc[a] = bv;                                                             \
  }                                                                          \
  {                                                                          \
    short8 ax = z8;                                                          \
    if (q == 0) ax = *(const short8*)&x_st[CN][c * 264 + (T) * 8];           \
    _Pragma("unroll") for (int a = 0; a < 4; ++a)                            \
        acc[a] = __builtin_amdgcn_mfma_f32_16x16x32_bf16(ax, Bh[a][4],       \
                                                         acc[a], 0, 0, 0);   \
  }

#define GATES_H(CN, T)                                                       \
  {                                                                          \
    const unsigned short* hb = hA[CN][((T) + 1) & 1];                        \
    _Pragma("unroll") for (int kt = 0; kt < 4; ++kt) {                       \
      const short8 ah = *(const short8*)&hb[kt * 512 + L * 8];               \
      _Pragma("unroll") for (int a = 0; a < 4; ++a)                          \
          acc[a] = __builtin_amdgcn_mfma_f32_16x16x32_bf16(ah, Bh[a][kt],    \
                                                           acc[a], 0, 0, 0); \
    }                                                                        \
  }

#define ACT_STORE(CN, CAP, T)                                                \
  {                                                                          \
    unsigned short* hw = &hA[CN][(T) & 1][pbase];                            \
    _Pragma("unroll") for (int r = 0; r < 4; ++r) {                          \
      const float iv = frcp_(1.0f + fexp2(acc[0][r]));                       \
      const float fv = frcp_(1.0f + fexp2(acc[1][r]));                       \
      const float gv = 2.0f * frcp_(1.0f + fexp2(acc[2][r])) - 1.0f;         \
      const float ov = frcp_(1.0f + fexp2(acc[3][r]));                       \
      const float cv = fv * cc[CN][r] + iv * gv;                             \
      cc[CN][r] = cv;                                                        \
      const float ec = fexp2(cv * -2.88539008f);                             \
      const float th = 2.0f * frcp_(1.0f + ec) - 1.0f;                       \
      const unsigned short hb16 = f2bf(ov * th);                             \
      hw[r * 8] = hb16;                                                      \
      if (CAP) {                                                             \
        if (((tpck[CN] >> (r * 8)) & 255u) == (unsigned)(T))                 \
          xtsb[CN][pbase + r * 8] = hb16;                                    \
      }                                                                      \
    }                                                                        \
  }

#define STEP_FULL(CN, CAP, T) \
  { GATES_X(CN, T) GATES_H(CN, T) ACT_STORE(CN, CAP, T) }
#define STEP_X(CN, CAP) { GATES_X(CN, 0) ACT_STORE(CN, CAP, 0) }

__global__ __launch_bounds__(BLOCK, 4) void recdqn_kernel(
    const float* __restrict__ s, const float* __restrict__ W_os,
    const float* __restrict__ b_os, const float* __restrict__ W_ih,
    const float* __restrict__ W_hh, const float* __restrict__ b_ih,
    const float* __restrict__ b_hh, const float* __restrict__ W_ts,
    const float* __restrict__ b_ts, const float* __restrict__ W_c1,
    const float* __restrict__ b_c1, const float* __restrict__ W_c2,
    const float* __restrict__ b_c2, const int* __restrict__ ws,
    float* __restrict__ out) {
  __shared__ unsigned short x_st[2][ROWS * 264]; // [chain][row][t][8] bf16
  __shared__ unsigned short hA[2][2][2048];      // [chain][buf] h A-frag
  __shared__ unsigned short xtsb[2][2048];       // captured h at t=len-1
  __shared__ unsigned short xcat[4096];          // concat A-frag (K=256), shared
  __shared__ unsigned short x2b[2048];           // W_c1 out A-frag, shared
  __shared__ int n_lds[2][ROWS];
  __shared__ int rid_s[2][ROWS];
  __shared__ int tmax_sh[2];
  __shared__ int uni_sh[2];

  const int tid = threadIdx.x;
  const int L = tid & 63;
  const int w = tid >> 6;   // wave 0..7: hidden cols [16w, 16w+16)
  const int c = L & 15;
  const int q = L >> 4;
  const int j = (w << 4) | c;

  const short8 z8 = {0, 0, 0, 0, 0, 0, 0, 0};

  // ---- one-time: prescaled W_hh/W_ih B-fragments + bias, register-resident
  short8 Bh[4][5];
  float bias[4];
#pragma unroll
  for (int a = 0; a < 4; ++a) {
    const float sc = (a == 2) ? -2.88539008f : -1.44269504f;
    const int n = (a << 7) + j;
    bias[a] = sc * (b_ih[n] + b_hh[n]);
#pragma unroll
    for (int kt = 0; kt < 4; ++kt)
      Bh[a][kt] = pack8s(W_hh + n * HID + kt * 32 + q * 8, sc);
    short8 fx = z8;
    if (q == 0) {
      const float* px = W_ih + n * NOBS_TS;
      fx[0] = (short)f2bf(px[0] * sc); fx[1] = (short)f2bf(px[1] * sc);
      fx[2] = (short)f2bf(px[2] * sc); fx[3] = (short)f2bf(px[3] * sc);
      fx[4] = (short)f2bf(px[4] * sc); fx[5] = (short)f2bf(px[5] * sc);
    }
    Bh[a][4] = fx;
  }

  const int pbase = ((j >> 5) << 9) + (((j >> 3) & 3) << 7) + (q << 5) + (j & 7);

  // ---- pick tile pair: adjacent sorted tiles, longest pairs first
  const int p = (PAIRS - 1) - blockIdx.x;
  if (tid < 32) {
    const int cn = tid >> 4, rr = tid & 15;
    const int row = ws[PERM_OFF + (2 * p + cn) * ROWS + rr];
    rid_s[cn][rr] = row;
    n_lds[cn][rr] = ws[LEN_OFF + row];
  }
  ((short8*)xtsb)[tid % 512] = z8; // 4096 shorts = 512 short8
  __syncthreads();

  // ---- stage s_TS -> LDS bf16 for both chains (zeros past length)
#pragma unroll
  for (int it = 0; it < 2; ++it) {
    const int slot = tid + it * 512;
    const int cn = slot >> 9, rt = slot & 511, r = rt >> 5, tq = rt & 31;
    short8 v = z8;
    if (tq < n_lds[cn][r]) {
      const float2* ps =
          (const float2*)(s + (size_t)rid_s[cn][r] * 200 + NOBS_OS + tq * NOBS_TS);
      const float2 A = ps[0], Bv = ps[1], Cv = ps[2];
      v[0] = (short)f2bf(A.x); v[1] = (short)f2bf(A.y);
      v[2] = (short)f2bf(Bv.x); v[3] = (short)f2bf(Bv.y);
      v[4] = (short)f2bf(Cv.x); v[5] = (short)f2bf(Cv.y);
    }
    *(short8*)&x_st[cn][r * 264 + tq * 8] = v;
  }
  if (tid == 0) {
#pragma unroll
    for (int cn = 0; cn < 2; ++cn) {
      int mx = 0, mn = 64;
      for (int r = 0; r < ROWS; ++r) {
        const int len = n_lds[cn][r];
        mx = max(mx, len);
        mn = min(mn, len);
      }
      tmax_sh[cn] = mx;
      uni_sh[cn] = (mx == mn);
    }
  }
  __syncthreads();

  const int tmA = tmax_sh[0], tmB = tmax_sh[1]; // tmA <= tmB (sorted)
  const bool fast = uni_sh[0] && uni_sh[1];
  unsigned tpck[2];
#pragma unroll
  for (int cn = 0; cn < 2; ++cn) {
    unsigned pk = 0;
#pragma unroll
    for (int b = 0; b < 4; ++b)
      pk |= ((unsigned)((n_lds[cn][q * 4 + b] - 1) & 255)) << (b * 8);
    tpck[cn] = pk;
  }

  float cc[2][4];
#pragma unroll
  for (int i = 0; i < 4; ++i) { cc[0][i] = 0.0f; cc[1][i] = 0.0f; }

  // ---- interleaved dual-chain LSTM time loop
  if (fast) {
    if (tmB > 0) {
      if (tmA > 0) STEP_X(0, 0)
      STEP_X(1, 0)
      __syncthreads();
      int t = 1;
      for (; t < tmA; ++t) {
        STEP_FULL(0, 0, t)
        STEP_FULL(1, 0, t)
        __syncthreads();
      }
      for (; t < tmB; ++t) {
        STEP_FULL(1, 0, t)
        __syncthreads();
      }
    }
    // uniform tiles: xts = h at t=tmax-1, one-shot copy
    if (tmA > 0 && tid < 256)
      ((short8*)xtsb[0])[tid] = ((const short8*)hA[0][(tmA + 1) & 1])[tid];
    if (tmB > 0 && tid >= 256)
      ((short8*)xtsb[1])[tid - 256] =
          ((const short8*)hA[1][(tmB + 1) & 1])[tid - 256];
  } else {
    if (tmB > 0) {
      if (tmA > 0) STEP_X(0, 1)
      STEP_X(1, 1)
      __syncthreads();
      for (int t = 1; t < tmB; ++t) {
        if (t < tmA) STEP_FULL(0, 1, t)
        STEP_FULL(1, 1, t)
        __syncthreads();
      }
    }
  }
  __syncthreads();

  // ---- heads, per chain (shared xcat/x2b)
#pragma unroll 1
  for (int cn = 0; cn < 2; ++cn) {
    // x_TS = relu(xts @ W_ts^T + b_ts) -> xcat k=128+j
    {
      const float bb = b_ts[j];
      f32x4 a2 = {bb, bb, bb, bb};
#pragma unroll
      for (int kt = 0; kt < 4; ++kt) {
        const short8 af = *(const short8*)&xtsb[cn][kt * 512 + L * 8];
        const f32x4* pp = (const f32x4*)(W_ts + j * HID + kt * 32 + q * 8);
        a2 = __builtin_amdgcn_mfma_f32_16x16x32_bf16(af, pack8(pp[0], pp[1]),
                                                     a2, 0, 0, 0);
      }
#pragma unroll
      for (int r = 0; r < 4; ++r)
        xcat[2048 + pbase + r * 8] = f2bf(fmaxf(a2[r], 0.0f));
    }
    // x_OS = relu(s_OS @ W_os^T + b_os) -> xcat k=j
    {
      short8 aos = z8, bos = z8;
      if (q == 0) {
        const f32x4* pa = (const f32x4*)(s + (size_t)rid_s[cn][c] * 200);
        aos = pack8(pa[0], pa[1]);
        const f32x4* pb = (const f32x4*)(W_os + j * NOBS_OS);
        bos = pack8(pb[0], pb[1]);
      }
      const float bb = b_os[j];
      f32x4 a2 = {bb, bb, bb, bb};
      a2 = __builtin_amdgcn_mfma_f32_16x16x32_bf16(aos, bos, a2, 0, 0, 0);
#pragma unroll
      for (int r = 0; r < 4; ++r)
        xcat[pbase + r * 8] = f2bf(fmaxf(a2[r], 0.0f));
    }
    __syncthreads();
    // x = relu(xcat @ W_c1^T + b_c1) -> x2b (K=256)
    {
      const float bb = b_c1[j];
      f32x4 a2 = {bb, bb, bb, bb};
#pragma unroll
      for (int kt = 0; kt < 8; ++kt) {
        const short8 af = *(const short8*)&xcat[kt * 512 + L * 8];
        const f32x4* pp = (const f32x4*)(W_c1 + j * 256 + kt * 32 + q * 8);
        a2 = __builtin_amdgcn_mfma_f32_16x16x32_bf16(af, pack8(pp[0], pp[1]),
                                                     a2, 0, 0, 0);
      }
#pragma unroll
      for (int r = 0; r < 4; ++r)
        x2b[pbase + r * 8] = f2bf(fmaxf(a2[r], 0.0f));
    }
    __syncthreads();
    // out = x2 @ W_c2^T + b_c2 (wave 0; cols c<9 valid)
    if (w == 0) {
      const float bb = (c < NACT) ? b_c2[c] : 0.0f;
      f32x4 accf = {bb, bb, bb, bb};
#pragma unroll
      for (int kt = 0; kt < 4; ++kt) {
        const short8 af = *(const short8*)&x2b[kt * 512 + L * 8];
        short8 bf = z8;
        if (c < NACT) {
          const f32x4* pp = (const f32x4*)(W_c2 + c * HID + kt * 32 + q * 8);
          bf = pack8(pp[0], pp[1]);
        }
        accf = __builtin_amdgcn_mfma_f32_16x16x32_bf16(af, bf, accf, 0, 0, 0);
      }
      if (c < NACT) {
#pragma unroll
        for (int r = 0; r < 4; ++r)
          out[(size_t)rid_s[cn][q * 4 + r] * NACT + c] = accf[r];
      }
    }
    __syncthreads(); // protect xcat/x2b reuse by next chain
  }
}

extern "C" void kernel_launch(void* const* d_in, const int* in_sizes, int n_in,
                              void* d_out, int out_size, void* d_ws, size_t ws_size,
                              hipStream_t stream) {
  (void)in_sizes; (void)n_in; (void)out_size; (void)ws_size;
  const float* s    = (const float*)d_in[0];
  const float* W_os = (const float*)d_in[1];
  const float* b_os = (const float*)d_in[2];
  const float* W_ih = (const float*)d_in[3];
  const float* W_hh = (const float*)d_in[4];
  const float* b_ih = (const float*)d_in[5];
  const float* b_hh = (const float*)d_in[6];
  const float* W_ts = (const float*)d_in[7];
  const float* b_ts = (const float*)d_in[8];
  const float* W_c1 = (const float*)d_in[9];
  const float* b_c1 = (const float*)d_in[10];
  const float* W_c2 = (const float*)d_in[11];
  const float* b_c2 = (const float*)d_in[12];
  int* ws = (int*)d_ws;
  float* outp = (float*)d_out;

  zero_hist_kernel<<<1, 128, 0, stream>>>(ws);
  count_kernel<<<BTOT / 256, 256, 0, stream>>>(s, ws);
  scan_kernel<<<1, 64, 0, stream>>>(ws);
  scatter_kernel<<<BTOT / 256, 256, 0, stream>>>(ws);
  recdqn_kernel<<<PAIRS, BLOCK, 0, stream>>>(
      s, W_os, b_os, W_ih, W_hh, b_ih, b_hh, W_ts, b_ts, W_c1, b_c1, W_c2,
      b_c2, ws, outp);
}

// Round 7
// 283.282 us; speedup vs baseline: 1.9461x; 1.2415x over previous
//
#include <hip/hip_runtime.h>

#ifndef __has_builtin
#define __has_builtin(x) 0
#endif

#define NOBS_OS 8
#define NOBS_TS 6
#define HID 128
#define NACT 9
#define BTOT 32768
#define NTS 32
#define ROWS 16        // batch rows per tile
#define NTILES 2048    // 2048*16 = 32768
#define PAIRS 1024     // one block per pair of adjacent sorted tiles
#define BLOCK 512      // 8 waves; wave w owns hidden cols [16w,16w+16)

// workspace layout (int32 offsets)
#define HIST_OFF 0
#define OFFS_OFF 64
#define LEN_OFF 128
#define PERM_OFF (128 + BTOT)

typedef __attribute__((ext_vector_type(8))) short short8;
typedef __attribute__((ext_vector_type(4))) float f32x4;

__device__ inline unsigned short f2bf(float x) {
  unsigned int u = __float_as_uint(x);
  u += 0x7FFFu + ((u >> 16) & 1u);
  return (unsigned short)(u >> 16);
}

__device__ inline float fexp2(float x) {
#if __has_builtin(__builtin_amdgcn_exp2f)
  return __builtin_amdgcn_exp2f(x);
#else
  return exp2f(x);
#endif
}
__device__ inline float frcp_(float x) {
#if __has_builtin(__builtin_amdgcn_rcpf)
  return __builtin_amdgcn_rcpf(x);
#else
  return 1.0f / x;
#endif
}

__device__ inline short8 pack8(f32x4 a, f32x4 b) {
  short8 r;
  r[0] = (short)f2bf(a[0]); r[1] = (short)f2bf(a[1]);
  r[2] = (short)f2bf(a[2]); r[3] = (short)f2bf(a[3]);
  r[4] = (short)f2bf(b[0]); r[5] = (short)f2bf(b[1]);
  r[6] = (short)f2bf(b[2]); r[7] = (short)f2bf(b[3]);
  return r;
}

__device__ inline short8 pack8s(const float* p, float s) {
  short8 r;
#pragma unroll
  for (int i = 0; i < 8; ++i) r[i] = (short)f2bf(p[i] * s);
  return r;
}

// ---- counting-sort pre-pass (LDS-aggregated) ----------------------------
__global__ void zero_hist_kernel(int* ws) {
  if (threadIdx.x < 128) ws[threadIdx.x] = 0;
}

__global__ void count_kernel(const float* __restrict__ s, int* __restrict__ ws) {
  __shared__ int lh[NTS + 1];
  const int tid = threadIdx.x;
  if (tid <= NTS) lh[tid] = 0;
  __syncthreads();
  const int row = blockIdx.x * 256 + tid;
  const float* p = s + (size_t)row * 200 + NOBS_OS;
  int lo = 0, hi = NTS;
  while (lo < hi) {
    const int mid = (lo + hi) >> 1;
    const float v = p[mid * NOBS_TS];
    if (v == v) lo = mid + 1; else hi = mid;
  }
  ws[LEN_OFF + row] = lo;
  atomicAdd(&lh[lo], 1);
  __syncthreads();
  if (tid <= NTS && lh[tid]) atomicAdd(&ws[HIST_OFF + tid], lh[tid]);
}

__global__ void scan_kernel(int* ws) {
  if (threadIdx.x == 0) {
    int acc = 0;
    for (int i = 0; i <= NTS; ++i) {
      ws[OFFS_OFF + i] = acc;
      acc += ws[HIST_OFF + i];
    }
  }
}

__global__ void scatter_kernel(int* __restrict__ ws) {
  __shared__ int lh[NTS + 1];
  __shared__ int lbase[NTS + 1];
  const int tid = threadIdx.x;
  if (tid <= NTS) lh[tid] = 0;
  __syncthreads();
  const int row = blockIdx.x * 256 + tid;
  const int len = ws[LEN_OFF + row];
  const int lrank = atomicAdd(&lh[len], 1);
  __syncthreads();
  if (tid <= NTS && lh[tid]) lbase[tid] = atomicAdd(&ws[OFFS_OFF + tid], lh[tid]);
  __syncthreads();
  ws[PERM_OFF + lbase[len] + lrank] = row;
}

// ---- main fused kernel --------------------------------------------------
// A-frag layout in LDS (16 rows x K): elem idx = kt*512 + lane*8 + jj
// C-layout writes at column k: idx = (k>>5)*512 + ((k>>3)&3)*128 + m*8 + (k&7)
// Weights prescaled: i,f,o by -1/log2(e), g by -2/log2(e) so that
//   sigmoid(x) = rcp(1+exp2(y)),  tanh(x) = 2*rcp(1+exp2(y)) - 1.

#define GATES_X(CN, T)                                                       \
  f32x4 acc[4];                                                              \
  _Pragma("unroll") for (int a = 0; a < 4; ++a) {                            \
    const float bb = bias[a];                                                \
    f32x4 bv = {bb, bb, bb, bb};                                             \
    acc[a] = bv;                                                             \
  }                                                                          \
  {                                                                          \
    short8 ax = z8;                                                          \
    if (q == 0) ax = *(const short8*)&x_st[CN][c * 264 + (T) * 8];           \
    _Pragma("unroll") for (int a = 0; a < 4; ++a)                            \
        acc[a] = __builtin_amdgcn_mfma_f32_16x16x32_bf16(ax, Bh[a][4],       \
                                                         acc[a], 0, 0, 0);   \
  }

#define GATES_H(CN, T)                                                       \
  {                                                                          \
    const unsigned short* hb = hA[CN][((T) + 1) & 1];                        \
    _Pragma("unroll") for (int kt = 0; kt < 4; ++kt) {                       \
      const short8 ah = *(const short8*)&hb[kt * 512 + L * 8];               \
      _Pragma("unroll") for (int a = 0; a < 4; ++a)                          \
          acc[a] = __builtin_amdgcn_mfma_f32_16x16x32_bf16(ah, Bh[a][kt],    \
                                                           acc[a], 0, 0, 0); \
    }                                                                        \
  }

#define ACT_STORE(CN, CAP, T)                                                \
  {                                                                          \
    unsigned short* hw = &hA[CN][(T) & 1][pbase];                            \
    _Pragma("unroll") for (int r = 0; r < 4; ++r) {                          \
      const float iv = frcp_(1.0f + fexp2(acc[0][r]));                       \
      const float fv = frcp_(1.0f + fexp2(acc[1][r]));                       \
      const float gv = 2.0f * frcp_(1.0f + fexp2(acc[2][r])) - 1.0f;         \
      const float ov = frcp_(1.0f + fexp2(acc[3][r]));                       \
      const float cv = fv * cc[CN][r] + iv * gv;                             \
      cc[CN][r] = cv;                                                        \
      const float ec = fexp2(cv * -2.88539008f);                             \
      const float th = 2.0f * frcp_(1.0f + ec) - 1.0f;                       \
      const unsigned short hb16 = f2bf(ov * th);                             \
      hw[r * 8] = hb16;                                                      \
      if (CAP) {                                                             \
        if (((tpck[CN] >> (r * 8)) & 255u) == (unsigned)(T))                 \
          xtsb[CN][pbase + r * 8] = hb16;                                    \
      }                                                                      \
    }                                                                        \
  }

#define STEP_FULL(CN, CAP, T) \
  { GATES_X(CN, T) GATES_H(CN, T) ACT_STORE(CN, CAP, T) }
#define STEP_X(CN, CAP) { GATES_X(CN, 0) ACT_STORE(CN, CAP, 0) }

__global__ __launch_bounds__(BLOCK, 2) void recdqn_kernel(
    const float* __restrict__ s, const float* __restrict__ W_os,
    const float* __restrict__ b_os, const float* __restrict__ W_ih,
    const float* __restrict__ W_hh, const float* __restrict__ b_ih,
    const float* __restrict__ b_hh, const float* __restrict__ W_ts,
    const float* __restrict__ b_ts, const float* __restrict__ W_c1,
    const float* __restrict__ b_c1, const float* __restrict__ W_c2,
    const float* __restrict__ b_c2, const int* __restrict__ ws,
    float* __restrict__ out) {
  __shared__ unsigned short x_st[2][ROWS * 264]; // [chain][row][t][8] bf16
  __shared__ unsigned short hA[2][2][2048];      // [chain][buf] h A-frag
  __shared__ unsigned short xtsb[2][2048];       // captured h at t=len-1
  __shared__ unsigned short xcat[4096];          // concat A-frag (K=256), shared
  __shared__ unsigned short x2b[2048];           // W_c1 out A-frag, shared
  __shared__ int n_lds[2][ROWS];
  __shared__ int rid_s[2][ROWS];
  __shared__ int tmax_sh[2];
  __shared__ int uni_sh[2];

  const int tid = threadIdx.x;
  const int L = tid & 63;
  const int w = tid >> 6;   // wave 0..7: hidden cols [16w, 16w+16)
  const int c = L & 15;
  const int q = L >> 4;
  const int j = (w << 4) | c;

  const short8 z8 = {0, 0, 0, 0, 0, 0, 0, 0};

  // ---- one-time: prescaled W_hh/W_ih B-fragments + bias, register-resident
  short8 Bh[4][5];
  float bias[4];
#pragma unroll
  for (int a = 0; a < 4; ++a) {
    const float sc = (a == 2) ? -2.88539008f : -1.44269504f;
    const int n = (a << 7) + j;
    bias[a] = sc * (b_ih[n] + b_hh[n]);
#pragma unroll
    for (int kt = 0; kt < 4; ++kt)
      Bh[a][kt] = pack8s(W_hh + n * HID + kt * 32 + q * 8, sc);
    short8 fx = z8;
    if (q == 0) {
      const float* px = W_ih + n * NOBS_TS;
      fx[0] = (short)f2bf(px[0] * sc); fx[1] = (short)f2bf(px[1] * sc);
      fx[2] = (short)f2bf(px[2] * sc); fx[3] = (short)f2bf(px[3] * sc);
      fx[4] = (short)f2bf(px[4] * sc); fx[5] = (short)f2bf(px[5] * sc);
    }
    Bh[a][4] = fx;
  }

  const int pbase = ((j >> 5) << 9) + (((j >> 3) & 3) << 7) + (q << 5) + (j & 7);

  // ---- pick tile pair: adjacent sorted tiles, longest pairs first
  const int p = (PAIRS - 1) - blockIdx.x;
  if (tid < 32) {
    const int cn = tid >> 4, rr = tid & 15;
    const int row = ws[PERM_OFF + (2 * p + cn) * ROWS + rr];
    rid_s[cn][rr] = row;
    n_lds[cn][rr] = ws[LEN_OFF + row];
  }
  ((short8*)xtsb)[tid % 512] = z8; // 4096 shorts = 512 short8
  __syncthreads();

  // ---- stage s_TS -> LDS bf16 for both chains (zeros past length)
#pragma unroll
  for (int it = 0; it < 2; ++it) {
    const int slot = tid + it * 512;
    const int cn = slot >> 9, rt = slot & 511, r = rt >> 5, tq = rt & 31;
    short8 v = z8;
    if (tq < n_lds[cn][r]) {
      const float2* ps =
          (const float2*)(s + (size_t)rid_s[cn][r] * 200 + NOBS_OS + tq * NOBS_TS);
      const float2 A = ps[0], Bv = ps[1], Cv = ps[2];
      v[0] = (short)f2bf(A.x); v[1] = (short)f2bf(A.y);
      v[2] = (short)f2bf(Bv.x); v[3] = (short)f2bf(Bv.y);
      v[4] = (short)f2bf(Cv.x); v[5] = (short)f2bf(Cv.y);
    }
    *(short8*)&x_st[cn][r * 264 + tq * 8] = v;
  }
  if (tid == 0) {
#pragma unroll
    for (int cn = 0; cn < 2; ++cn) {
      int mx = 0, mn = 64;
      for (int r = 0; r < ROWS; ++r) {
        const int len = n_lds[cn][r];
        mx = max(mx, len);
        mn = min(mn, len);
      }
      tmax_sh[cn] = mx;
      uni_sh[cn] = (mx == mn);
    }
  }
  __syncthreads();

  const int tmA = tmax_sh[0], tmB = tmax_sh[1]; // tmA <= tmB (sorted)
  const bool fast = uni_sh[0] && uni_sh[1];
  unsigned tpck[2] = {0u, 0u};
  if (!fast) {
#pragma unroll
    for (int cn = 0; cn < 2; ++cn) {
      unsigned pk = 0;
#pragma unroll
      for (int b = 0; b < 4; ++b)
        pk |= ((unsigned)((n_lds[cn][q * 4 + b] - 1) & 255)) << (b * 8);
      tpck[cn] = pk;
    }
  }

  float cc[2][4];
#pragma unroll
  for (int i = 0; i < 4; ++i) { cc[0][i] = 0.0f; cc[1][i] = 0.0f; }

  // ---- interleaved dual-chain LSTM time loop
  if (fast) {
    if (tmB > 0) {
      if (tmA > 0) STEP_X(0, 0)
      STEP_X(1, 0)
      __syncthreads();
      int t = 1;
      for (; t < tmA; ++t) {
        STEP_FULL(0, 0, t)
        STEP_FULL(1, 0, t)
        __syncthreads();
      }
      for (; t < tmB; ++t) {
        STEP_FULL(1, 0, t)
        __syncthreads();
      }
    }
    // uniform tiles: xts = h at t=tmax-1, one-shot copy
    if (tmA > 0 && tid < 256)
      ((short8*)xtsb[0])[tid] = ((const short8*)hA[0][(tmA + 1) & 1])[tid];
    if (tmB > 0 && tid >= 256)
      ((short8*)xtsb[1])[tid - 256] =
          ((const short8*)hA[1][(tmB + 1) & 1])[tid - 256];
  } else {
    if (tmB > 0) {
      if (tmA > 0) STEP_X(0, 1)
      STEP_X(1, 1)
      __syncthreads();
      for (int t = 1; t < tmB; ++t) {
        if (t < tmA) STEP_FULL(0, 1, t)
        STEP_FULL(1, 1, t)
        __syncthreads();
      }
    }
  }
  __syncthreads();

  // ---- heads, per chain (shared xcat/x2b)
#pragma unroll 1
  for (int cn = 0; cn < 2; ++cn) {
    // x_TS = relu(xts @ W_ts^T + b_ts) -> xcat k=128+j
    {
      const float bb = b_ts[j];
      f32x4 a2 = {bb, bb, bb, bb};
#pragma unroll
      for (int kt = 0; kt < 4; ++kt) {
        const short8 af = *(const short8*)&xtsb[cn][kt * 512 + L * 8];
        const f32x4* pp = (const f32x4*)(W_ts + j * HID + kt * 32 + q * 8);
        a2 = __builtin_amdgcn_mfma_f32_16x16x32_bf16(af, pack8(pp[0], pp[1]),
                                                     a2, 0, 0, 0);
      }
#pragma unroll
      for (int r = 0; r < 4; ++r)
        xcat[2048 + pbase + r * 8] = f2bf(fmaxf(a2[r], 0.0f));
    }
    // x_OS = relu(s_OS @ W_os^T + b_os) -> xcat k=j
    {
      short8 aos = z8, bos = z8;
      if (q == 0) {
        const f32x4* pa = (const f32x4*)(s + (size_t)rid_s[cn][c] * 200);
        aos = pack8(pa[0], pa[1]);
        const f32x4* pb = (const f32x4*)(W_os + j * NOBS_OS);
        bos = pack8(pb[0], pb[1]);
      }
      const float bb = b_os[j];
      f32x4 a2 = {bb, bb, bb, bb};
      a2 = __builtin_amdgcn_mfma_f32_16x16x32_bf16(aos, bos, a2, 0, 0, 0);
#pragma unroll
      for (int r = 0; r < 4; ++r)
        xcat[pbase + r * 8] = f2bf(fmaxf(a2[r], 0.0f));
    }
    __syncthreads();
    // x = relu(xcat @ W_c1^T + b_c1) -> x2b (K=256)
    {
      const float bb = b_c1[j];
      f32x4 a2 = {bb, bb, bb, bb};
#pragma unroll
      for (int kt = 0; kt < 8; ++kt) {
        const short8 af = *(const short8*)&xcat[kt * 512 + L * 8];
        const f32x4* pp = (const f32x4*)(W_c1 + j * 256 + kt * 32 + q * 8);
        a2 = __builtin_amdgcn_mfma_f32_16x16x32_bf16(af, pack8(pp[0], pp[1]),
                                                     a2, 0, 0, 0);
      }
#pragma unroll
      for (int r = 0; r < 4; ++r)
        x2b[pbase + r * 8] = f2bf(fmaxf(a2[r], 0.0f));
    }
    __syncthreads();
    // out = x2 @ W_c2^T + b_c2 (wave 0; cols c<9 valid)
    if (w == 0) {
      const float bb = (c < NACT) ? b_c2[c] : 0.0f;
      f32x4 accf = {bb, bb, bb, bb};
#pragma unroll
      for (int kt = 0; kt < 4; ++kt) {
        const short8 af = *(const short8*)&x2b[kt * 512 + L * 8];
        short8 bf = z8;
        if (c < NACT) {
          const f32x4* pp = (const f32x4*)(W_c2 + c * HID + kt * 32 + q * 8);
          bf = pack8(pp[0], pp[1]);
        }
        accf = __builtin_amdgcn_mfma_f32_16x16x32_bf16(af, bf, accf, 0, 0, 0);
      }
      if (c < NACT) {
#pragma unroll
        for (int r = 0; r < 4; ++r)
          out[(size_t)rid_s[cn][q * 4 + r] * NACT + c] = accf[r];
      }
    }
    __syncthreads(); // protect xcat/x2b reuse by next chain
  }
}

extern "C" void kernel_launch(void* const* d_in, const int* in_sizes, int n_in,
                              void* d_out, int out_size, void* d_ws, size_t ws_size,
                              hipStream_t stream) {
  (void)in_sizes; (void)n_in; (void)out_size; (void)ws_size;
  const float* s    = (const float*)d_in[0];
  const float* W_os = (const float*)d_in[1];
  const float* b_os = (const float*)d_in[2];
  const float* W_ih = (const float*)d_in[3];
  const float* W_hh = (const float*)d_in[4];
  const float* b_ih = (const float*)d_in[5];
  const float* b_hh = (const float*)d_in[6];
  const float* W_ts = (const float*)d_in[7];
  const float* b_ts = (const float*)d_in[8];
  const float* W_c1 = (const float*)d_in[9];
  const float* b_c1 = (const float*)d_in[10];
  const float* W_c2 = (const float*)d_in[11];
  const float* b_c2 = (const float*)d_in[12];
  int* ws = (int*)d_ws;
  float* outp = (float*)d_out;

  zero_hist_kernel<<<1, 128, 0, stream>>>(ws);
  count_kernel<<<BTOT / 256, 256, 0, stream>>>(s, ws);
  scan_kernel<<<1, 64, 0, stream>>>(ws);
  scatter_kernel<<<BTOT / 256, 256, 0, stream>>>(ws);
  recdqn_kernel<<<PAIRS, BLOCK, 0, stream>>>(
      s, W_os, b_os, W_ih, W_hh, b_ih, b_hh, W_ts, b_ts, W_c1, b_c1, W_c2,
      b_c2, ws, outp);
}

// Round 8
// 277.282 us; speedup vs baseline: 1.9882x; 1.0216x over previous
//
#include <hip/hip_runtime.h>

#ifndef __has_builtin
#define __has_builtin(x) 0
#endif

#define NOBS_OS 8
#define NOBS_TS 6
#define HID 128
#define NACT 9
#define BTOT 32768
#define NTS 32
#define ROWS 16        // batch rows per tile
#define NTILES 2048    // 2048*16 = 32768
#define PAIRS 1024     // one block per pair of adjacent sorted tiles
#define BLOCK 512      // 8 waves; wave w owns hidden cols [16w,16w+16)

// workspace layout (int32 offsets)
#define HIST_OFF 0
#define OFFS_OFF 64
#define LEN_OFF 128
#define PERM_OFF (128 + BTOT)

typedef __attribute__((ext_vector_type(8))) short short8;
typedef __attribute__((ext_vector_type(4))) float f32x4;

__device__ inline unsigned short f2bf(float x) {
  unsigned int u = __float_as_uint(x);
  u += 0x7FFFu + ((u >> 16) & 1u);
  return (unsigned short)(u >> 16);
}

// packed f32x2 -> bf16x2 (low = a, high = b)
__device__ inline unsigned pkbf(float a, float b) {
#if __has_builtin(__builtin_amdgcn_cvt_pk_bf16_f32)
  auto v = __builtin_amdgcn_cvt_pk_bf16_f32(a, b);
  unsigned u;
  __builtin_memcpy(&u, &v, sizeof(u));
  return u;
#else
  return ((unsigned)f2bf(b) << 16) | (unsigned)f2bf(a);
#endif
}

__device__ inline float fexp2(float x) {
#if __has_builtin(__builtin_amdgcn_exp2f)
  return __builtin_amdgcn_exp2f(x);
#else
  return exp2f(x);
#endif
}
__device__ inline float frcp_(float x) {
#if __has_builtin(__builtin_amdgcn_rcpf)
  return __builtin_amdgcn_rcpf(x);
#else
  return 1.0f / x;
#endif
}

__device__ inline short8 pack8(f32x4 a, f32x4 b) {
  union { unsigned u[4]; short8 s; } r;
  r.u[0] = pkbf(a[0], a[1]); r.u[1] = pkbf(a[2], a[3]);
  r.u[2] = pkbf(b[0], b[1]); r.u[3] = pkbf(b[2], b[3]);
  return r.s;
}

__device__ inline short8 pack8s(const float* p, float s) {
  union { unsigned u[4]; short8 r; } r;
#pragma unroll
  for (int i = 0; i < 4; ++i) r.u[i] = pkbf(p[2 * i] * s, p[2 * i + 1] * s);
  return r.r;
}

// ---- counting-sort pre-pass (LDS-aggregated) ----------------------------
__global__ void zero_hist_kernel(int* ws) {
  if (threadIdx.x < 128) ws[threadIdx.x] = 0;
}

__global__ void count_kernel(const float* __restrict__ s, int* __restrict__ ws) {
  __shared__ int lh[NTS + 1];
  const int tid = threadIdx.x;
  if (tid <= NTS) lh[tid] = 0;
  __syncthreads();
  const int row = blockIdx.x * 256 + tid;
  const float* p = s + (size_t)row * 200 + NOBS_OS;
  int lo = 0, hi = NTS;
  while (lo < hi) {
    const int mid = (lo + hi) >> 1;
    const float v = p[mid * NOBS_TS];
    if (v == v) lo = mid + 1; else hi = mid;
  }
  ws[LEN_OFF + row] = lo;
  atomicAdd(&lh[lo], 1);
  __syncthreads();
  if (tid <= NTS && lh[tid]) atomicAdd(&ws[HIST_OFF + tid], lh[tid]);
}

__global__ void scan_kernel(int* ws) {
  if (threadIdx.x == 0) {
    int acc = 0;
    for (int i = 0; i <= NTS; ++i) {
      ws[OFFS_OFF + i] = acc;
      acc += ws[HIST_OFF + i];
    }
  }
}

__global__ void scatter_kernel(int* __restrict__ ws) {
  __shared__ int lh[NTS + 1];
  __shared__ int lbase[NTS + 1];
  const int tid = threadIdx.x;
  if (tid <= NTS) lh[tid] = 0;
  __syncthreads();
  const int row = blockIdx.x * 256 + tid;
  const int len = ws[LEN_OFF + row];
  const int lrank = atomicAdd(&lh[len], 1);
  __syncthreads();
  if (tid <= NTS && lh[tid]) lbase[tid] = atomicAdd(&ws[OFFS_OFF + tid], lh[tid]);
  __syncthreads();
  ws[PERM_OFF + lbase[len] + lrank] = row;
}

// ---- main fused kernel --------------------------------------------------
// A-frag layout in LDS (16 rows x K): elem idx = kt*512 + lane*8 + jj
// C-layout writes at column k: idx = (k>>5)*512 + ((k>>3)&3)*128 + m*8 + (k&7)
// Weights prescaled: i,f,o by -1/log2(e), g by -2/log2(e); fused products:
//   i*g       = (1-eg)*rcp((1+ei)(1+eg))
//   f*c       = c*rcp(1+ef)
//   o*tanh(c) = (1-ec)*rcp((1+eo)(1+ec)),  ec = exp2(-2c*log2e)
// => 5 exp2 + 3 rcp per hidden unit per step.

#define GATES_X(CN, T)                                                       \
  f32x4 acc[4];                                                              \
  _Pragma("unroll") for (int a = 0; a < 4; ++a) {                            \
    const float bb = bias[a];                                                \
    f32x4 bv = {bb, bb, bb, bb};                                             \
    acc[a] = bv;                                                             \
  }                                                                          \
  {                                                                          \
    short8 ax = z8;                                                          \
    if (q == 0) ax = *(const short8*)&x_st[CN][c * 264 + (T) * 8];           \
    _Pragma("unroll") for (int a = 0; a < 4; ++a)                            \
        acc[a] = __builtin_amdgcn_mfma_f32_16x16x32_bf16(ax, Bh[a][4],       \
                                                         acc[a], 0, 0, 0);   \
  }

#define GATES_H(CN, T)                                                       \
  {                                                                          \
    const unsigned short* hb = hA[CN][((T) + 1) & 1];                        \
    _Pragma("unroll") for (int kt = 0; kt < 4; ++kt) {                       \
      const short8 ah = *(const short8*)&hb[kt * 512 + L * 8];               \
      _Pragma("unroll") for (int a = 0; a < 4; ++a)                          \
          acc[a] = __builtin_amdgcn_mfma_f32_16x16x32_bf16(ah, Bh[a][kt],    \
                                                           acc[a], 0, 0, 0); \
    }                                                                        \
  }

#define ACT_STORE(CN, CAP, T)                                                \
  {                                                                          \
    unsigned short* hw = &hA[CN][(T) & 1][pbase];                            \
    float hv[4];                                                             \
    _Pragma("unroll") for (int r = 0; r < 4; ++r) {                          \
      const float ei = fexp2(acc[0][r]);                                     \
      const float ef = fexp2(acc[1][r]);                                     \
      const float eg = fexp2(acc[2][r]);                                     \
      const float eo = fexp2(acc[3][r]);                                     \
      const float rig = frcp_((1.0f + ei) * (1.0f + eg));                    \
      const float rf = frcp_(1.0f + ef);                                     \
      const float cv = cc[CN][r] * rf + (1.0f - eg) * rig;                   \
      cc[CN][r] = cv;                                                        \
      const float ec = fexp2(cv * -2.88539008f);                             \
      const float roc = frcp_((1.0f + eo) * (1.0f + ec));                    \
      hv[r] = (1.0f - ec) * roc;                                             \
    }                                                                        \
    const unsigned p01 = pkbf(hv[0], hv[1]);                                 \
    const unsigned p23 = pkbf(hv[2], hv[3]);                                 \
    const unsigned short h16[4] = {                                          \
        (unsigned short)p01, (unsigned short)(p01 >> 16),                    \
        (unsigned short)p23, (unsigned short)(p23 >> 16)};                   \
    _Pragma("unroll") for (int r = 0; r < 4; ++r) {                          \
      hw[r * 8] = h16[r];                                                    \
      if (CAP) {                                                             \
        if (((tpck[CN] >> (r * 8)) & 255u) == (unsigned)(T))                 \
          xtsb[CN][pbase + r * 8] = h16[r];                                  \
      }                                                                      \
    }                                                                        \
  }

#define STEP_FULL(CN, CAP, T) \
  { GATES_X(CN, T) GATES_H(CN, T) ACT_STORE(CN, CAP, T) }
#define STEP_X(CN, CAP) { GATES_X(CN, 0) ACT_STORE(CN, CAP, 0) }

__global__ __launch_bounds__(BLOCK, 2) void recdqn_kernel(
    const float* __restrict__ s, const float* __restrict__ W_os,
    const float* __restrict__ b_os, const float* __restrict__ W_ih,
    const float* __restrict__ W_hh, const float* __restrict__ b_ih,
    const float* __restrict__ b_hh, const float* __restrict__ W_ts,
    const float* __restrict__ b_ts, const float* __restrict__ W_c1,
    const float* __restrict__ b_c1, const float* __restrict__ W_c2,
    const float* __restrict__ b_c2, const int* __restrict__ ws,
    float* __restrict__ out) {
  __shared__ unsigned short x_st[2][ROWS * 264]; // [chain][row][t][8] bf16
  __shared__ unsigned short hA[2][2][2048];      // [chain][buf] h A-frag
  __shared__ unsigned short xtsb[2][2048];       // captured h at t=len-1
  __shared__ unsigned short xcat[4096];          // concat A-frag (K=256), shared
  __shared__ unsigned short x2b[2048];           // W_c1 out A-frag, shared
  __shared__ int n_lds[2][ROWS];
  __shared__ int rid_s[2][ROWS];
  __shared__ int tmax_sh[2];
  __shared__ int uni_sh[2];

  const int tid = threadIdx.x;
  const int L = tid & 63;
  const int w = tid >> 6;   // wave 0..7: hidden cols [16w, 16w+16)
  const int c = L & 15;
  const int q = L >> 4;
  const int j = (w << 4) | c;

  const short8 z8 = {0, 0, 0, 0, 0, 0, 0, 0};

  // ---- one-time: prescaled W_hh/W_ih B-fragments + bias, register-resident
  short8 Bh[4][5];
  float bias[4];
#pragma unroll
  for (int a = 0; a < 4; ++a) {
    const float sc = (a == 2) ? -2.88539008f : -1.44269504f;
    const int n = (a << 7) + j;
    bias[a] = sc * (b_ih[n] + b_hh[n]);
#pragma unroll
    for (int kt = 0; kt < 4; ++kt)
      Bh[a][kt] = pack8s(W_hh + n * HID + kt * 32 + q * 8, sc);
    short8 fx = z8;
    if (q == 0) {
      const float* px = W_ih + n * NOBS_TS;
      union { unsigned u[4]; short8 s; } fu;
      fu.u[0] = pkbf(px[0] * sc, px[1] * sc);
      fu.u[1] = pkbf(px[2] * sc, px[3] * sc);
      fu.u[2] = pkbf(px[4] * sc, px[5] * sc);
      fu.u[3] = 0;
      fx = fu.s;
    }
    Bh[a][4] = fx;
  }

  const int pbase = ((j >> 5) << 9) + (((j >> 3) & 3) << 7) + (q << 5) + (j & 7);

  // ---- pick tile pair: adjacent sorted tiles, longest pairs first
  const int p = (PAIRS - 1) - blockIdx.x;
  if (tid < 32) {
    const int cn = tid >> 4, rr = tid & 15;
    const int row = ws[PERM_OFF + (2 * p + cn) * ROWS + rr];
    rid_s[cn][rr] = row;
    n_lds[cn][rr] = ws[LEN_OFF + row];
  }
  ((short8*)xtsb)[tid % 512] = z8; // 4096 shorts = 512 short8
  __syncthreads();

  // ---- stage s_TS -> LDS bf16 for both chains (zeros past length)
#pragma unroll
  for (int it = 0; it < 2; ++it) {
    const int slot = tid + it * 512;
    const int cn = slot >> 9, rt = slot & 511, r = rt >> 5, tq = rt & 31;
    short8 v = z8;
    if (tq < n_lds[cn][r]) {
      const float2* ps =
          (const float2*)(s + (size_t)rid_s[cn][r] * 200 + NOBS_OS + tq * NOBS_TS);
      const float2 A = ps[0], Bv = ps[1], Cv = ps[2];
      union { unsigned u[4]; short8 s; } vu;
      vu.u[0] = pkbf(A.x, A.y);
      vu.u[1] = pkbf(Bv.x, Bv.y);
      vu.u[2] = pkbf(Cv.x, Cv.y);
      vu.u[3] = 0;
      v = vu.s;
    }
    *(short8*)&x_st[cn][r * 264 + tq * 8] = v;
  }
  if (tid == 0) {
#pragma unroll
    for (int cn = 0; cn < 2; ++cn) {
      int mx = 0, mn = 64;
      for (int r = 0; r < ROWS; ++r) {
        const int len = n_lds[cn][r];
        mx = max(mx, len);
        mn = min(mn, len);
      }
      tmax_sh[cn] = mx;
      uni_sh[cn] = (mx == mn);
    }
  }
  __syncthreads();

  const int tmA = tmax_sh[0], tmB = tmax_sh[1]; // tmA <= tmB (sorted)
  const bool fast = uni_sh[0] && uni_sh[1];
  unsigned tpck[2] = {0u, 0u};
  if (!fast) {
#pragma unroll
    for (int cn = 0; cn < 2; ++cn) {
      unsigned pk = 0;
#pragma unroll
      for (int b = 0; b < 4; ++b)
        pk |= ((unsigned)((n_lds[cn][q * 4 + b] - 1) & 255)) << (b * 8);
      tpck[cn] = pk;
    }
  }

  float cc[2][4];
#pragma unroll
  for (int i = 0; i < 4; ++i) { cc[0][i] = 0.0f; cc[1][i] = 0.0f; }

  // ---- interleaved dual-chain LSTM time loop
  if (fast) {
    if (tmB > 0) {
      if (tmA > 0) STEP_X(0, 0)
      STEP_X(1, 0)
      __syncthreads();
      int t = 1;
      for (; t < tmA; ++t) {
        STEP_FULL(0, 0, t)
        STEP_FULL(1, 0, t)
        __syncthreads();
      }
      for (; t < tmB; ++t) {
        STEP_FULL(1, 0, t)
        __syncthreads();
      }
    }
    // uniform tiles: xts = h at t=tmax-1, one-shot copy
    if (tmA > 0 && tid < 256)
      ((short8*)xtsb[0])[tid] = ((const short8*)hA[0][(tmA + 1) & 1])[tid];
    if (tmB > 0 && tid >= 256)
      ((short8*)xtsb[1])[tid - 256] =
          ((const short8*)hA[1][(tmB + 1) & 1])[tid - 256];
  } else {
    if (tmB > 0) {
      if (tmA > 0) STEP_X(0, 1)
      STEP_X(1, 1)
      __syncthreads();
      for (int t = 1; t < tmB; ++t) {
        if (t < tmA) STEP_FULL(0, 1, t)
        STEP_FULL(1, 1, t)
        __syncthreads();
      }
    }
  }
  __syncthreads();

  // ---- hoisted head weight fragments (bf16), reused by both chains
  short8 Fts[4], Fc1[8], Fc2[4], bosf = z8;
#pragma unroll
  for (int kt = 0; kt < 4; ++kt) {
    const f32x4* pp = (const f32x4*)(W_ts + j * HID + kt * 32 + q * 8);
    Fts[kt] = pack8(pp[0], pp[1]);
  }
#pragma unroll
  for (int kt = 0; kt < 8; ++kt) {
    const f32x4* pp = (const f32x4*)(W_c1 + j * 256 + kt * 32 + q * 8);
    Fc1[kt] = pack8(pp[0], pp[1]);
  }
#pragma unroll
  for (int kt = 0; kt < 4; ++kt) Fc2[kt] = z8;
  if (w == 0 && c < NACT) {
#pragma unroll
    for (int kt = 0; kt < 4; ++kt) {
      const f32x4* pp = (const f32x4*)(W_c2 + c * HID + kt * 32 + q * 8);
      Fc2[kt] = pack8(pp[0], pp[1]);
    }
  }
  if (q == 0) {
    const f32x4* pb = (const f32x4*)(W_os + j * NOBS_OS);
    bosf = pack8(pb[0], pb[1]);
  }
  const float bts = b_ts[j], bc1 = b_c1[j], bos = b_os[j];
  const float bc2 = (w == 0 && c < NACT) ? b_c2[c] : 0.0f;

  // ---- heads, per chain (shared xcat/x2b)
#pragma unroll 1
  for (int cn = 0; cn < 2; ++cn) {
    // x_TS = relu(xts @ W_ts^T + b_ts) -> xcat k=128+j
    {
      f32x4 a2 = {bts, bts, bts, bts};
#pragma unroll
      for (int kt = 0; kt < 4; ++kt) {
        const short8 af = *(const short8*)&xtsb[cn][kt * 512 + L * 8];
        a2 = __builtin_amdgcn_mfma_f32_16x16x32_bf16(af, Fts[kt], a2, 0, 0, 0);
      }
      const unsigned p01 = pkbf(fmaxf(a2[0], 0.0f), fmaxf(a2[1], 0.0f));
      const unsigned p23 = pkbf(fmaxf(a2[2], 0.0f), fmaxf(a2[3], 0.0f));
      xcat[2048 + pbase + 0] = (unsigned short)p01;
      xcat[2048 + pbase + 8] = (unsigned short)(p01 >> 16);
      xcat[2048 + pbase + 16] = (unsigned short)p23;
      xcat[2048 + pbase + 24] = (unsigned short)(p23 >> 16);
    }
    // x_OS = relu(s_OS @ W_os^T + b_os) -> xcat k=j
    {
      short8 aos = z8;
      if (q == 0) {
        const f32x4* pa = (const f32x4*)(s + (size_t)rid_s[cn][c] * 200);
        aos = pack8(pa[0], pa[1]);
      }
      f32x4 a2 = {bos, bos, bos, bos};
      a2 = __builtin_amdgcn_mfma_f32_16x16x32_bf16(aos, bosf, a2, 0, 0, 0);
      const unsigned p01 = pkbf(fmaxf(a2[0], 0.0f), fmaxf(a2[1], 0.0f));
      const unsigned p23 = pkbf(fmaxf(a2[2], 0.0f), fmaxf(a2[3], 0.0f));
      xcat[pbase + 0] = (unsigned short)p01;
      xcat[pbase + 8] = (unsigned short)(p01 >> 16);
      xcat[pbase + 16] = (unsigned short)p23;
      xcat[pbase + 24] = (unsigned short)(p23 >> 16);
    }
    __syncthreads();
    // x = relu(xcat @ W_c1^T + b_c1) -> x2b (K=256)
    {
      f32x4 a2 = {bc1, bc1, bc1, bc1};
#pragma unroll
      for (int kt = 0; kt < 8; ++kt) {
        const short8 af = *(const short8*)&xcat[kt * 512 + L * 8];
        a2 = __builtin_amdgcn_mfma_f32_16x16x32_bf16(af, Fc1[kt], a2, 0, 0, 0);
      }
      const unsigned p01 = pkbf(fmaxf(a2[0], 0.0f), fmaxf(a2[1], 0.0f));
      const unsigned p23 = pkbf(fmaxf(a2[2], 0.0f), fmaxf(a2[3], 0.0f));
      x2b[pbase + 0] = (unsigned short)p01;
      x2b[pbase + 8] = (unsigned short)(p01 >> 16);
      x2b[pbase + 16] = (unsigned short)p23;
      x2b[pbase + 24] = (unsigned short)(p23 >> 16);
    }
    __syncthreads();
    // out = x2 @ W_c2^T + b_c2 (wave 0; cols c<9 valid)
    if (w == 0) {
      f32x4 accf = {bc2, bc2, bc2, bc2};
#pragma unroll
      for (int kt = 0; kt < 4; ++kt) {
        const short8 af = *(const short8*)&x2b[kt * 512 + L * 8];
        accf = __builtin_amdgcn_mfma_f32_16x16x32_bf16(af, Fc2[kt], accf, 0, 0, 0);
      }
      if (c < NACT) {
#pragma unroll
        for (int r = 0; r < 4; ++r)
          out[(size_t)rid_s[cn][q * 4 + r] * NACT + c] = accf[r];
      }
    }
    __syncthreads(); // protect xcat/x2b reuse by next chain
  }
}

extern "C" void kernel_launch(void* const* d_in, const int* in_sizes, int n_in,
                              void* d_out, int out_size, void* d_ws, size_t ws_size,
                              hipStream_t stream) {
  (void)in_sizes; (void)n_in; (void)out_size; (void)ws_size;
  const float* s    = (const float*)d_in[0];
  const float* W_os = (const float*)d_in[1];
  const float* b_os = (const float*)d_in[2];
  const float* W_ih = (const float*)d_in[3];
  const float* W_hh = (const float*)d_in[4];
  const float* b_ih = (const float*)d_in[5];
  const float* b_hh = (const float*)d_in[6];
  const float* W_ts = (const float*)d_in[7];
  const float* b_ts = (const float*)d_in[8];
  const float* W_c1 = (const float*)d_in[9];
  const float* b_c1 = (const float*)d_in[10];
  const float* W_c2 = (const float*)d_in[11];
  const float* b_c2 = (const float*)d_in[12];
  int* ws = (int*)d_ws;
  float* outp = (float*)d_out;

  zero_hist_kernel<<<1, 128, 0, stream>>>(ws);
  count_kernel<<<BTOT / 256, 256, 0, stream>>>(s, ws);
  scan_kernel<<<1, 64, 0, stream>>>(ws);
  scatter_kernel<<<BTOT / 256, 256, 0, stream>>>(ws);
  recdqn_kernel<<<PAIRS, BLOCK, 0, stream>>>(
      s, W_os, b_os, W_ih, W_hh, b_ih, b_hh, W_ts, b_ts, W_c1, b_c1, W_c2,
      b_c2, ws, outp);
}